// Round 9
// baseline (657.855 us; speedup 1.0000x reference)
//
#include <hip/hip_runtime.h>
#include <cmath>
#include <type_traits>

typedef __bf16 bf16;
typedef __attribute__((ext_vector_type(8))) __bf16 bf16x8;
typedef __attribute__((ext_vector_type(4))) __bf16 bf16x4;
typedef __attribute__((ext_vector_type(4))) float f32x4;

__device__ __forceinline__ unsigned f2s(float x) {
    unsigned u = __float_as_uint(x);
    return (u & 0x80000000u) ? ~u : (u | 0x80000000u);
}
__device__ __forceinline__ float s2f(unsigned s) {
    return (s & 0x80000000u) ? __uint_as_float(s & 0x7FFFFFFFu)
                             : __uint_as_float(~s);
}

// mish(x) = x*tanh(softplus(x)) = x*(t^2+2t)/(t^2+2t+2), t=e^x (clamped; ratio->1)
__device__ __forceinline__ float fast_mish(float x) {
    const float t = __expf(fminf(x, 32.f));
    const float num = fmaf(t, t, t + t);   // (1+t)^2 - 1
    const float den = num + 2.f;           // (1+t)^2 + 1
    return x * num * __builtin_amdgcn_rcpf(den);
}

// ---------------- combined weight prep ----------------
__global__ void prep_weights_kernel(const float* __restrict__ W0, const float* __restrict__ W1,
                                    const float* __restrict__ W2, const float* __restrict__ rW2,
                                    bf16* __restrict__ Wt0, bf16* __restrict__ Wt1,
                                    bf16* __restrict__ Bct) {
    const int idx = blockIdx.x * blockDim.x + threadIdx.x;
    if (idx < 65536) {
        const int k = idx >> 8, m = idx & 255;
        Wt0[m * 256 + k] = (bf16)W0[idx];
        Wt1[m * 256 + k] = (bf16)W1[idx];
    }
    if (idx < 8192) {
        const int m = idx >> 8, k = idx & 255;
        const float v = (m < 16) ? W2[k * 16 + m] : rW2[k * 16 + (m - 16)];
        Bct[idx] = (bf16)v;
    }
}

// ---------------- MFMA GEMM + fused el/er/elmax epilogue ----------------
// Fb[N,256](bf16) = A[N,256] @ Bt^T. Each wave's 64 output cols span exactly one
// head h = 2*blockIdx.x + (wave&1); el/er computed from fp32 acc (4 FMA + 8 shfl
// per row), running max -> one atomicMax per quad. Replaces el_er_node + elmax4.
template <typename AT>
__global__ __launch_bounds__(256) void gemm_mfma_bf16(const AT* __restrict__ A,
                                                      const bf16* __restrict__ Bt,
                                                      bf16* __restrict__ Fb,
                                                      const float* __restrict__ al,
                                                      const float* __restrict__ ar,
                                                      float* __restrict__ el,
                                                      float* __restrict__ er,
                                                      unsigned* __restrict__ elmax_u, int N) {
    constexpr int K = 256, BM = 128, BK = 32;
    constexpr int LDA = BK + 8;
    __shared__ bf16 As[BM * LDA];
    __shared__ bf16 Bs[BM * LDA];

    const int tid = threadIdx.x;
    const int wave = tid >> 6, lane = tid & 63;
    const int quad = lane >> 4, l16 = lane & 15;
    const int rowBase = blockIdx.y * BM;
    const int colBase = blockIdx.x * BM;
    const int m_base = (wave >> 1) * 64, n_base = (wave & 1) * 64;

    f32x4 acc[4][4] = {};

    const int sr = tid >> 1;
    const int seg = (tid & 1) << 4;

    for (int k0 = 0; k0 < K; k0 += BK) {
        {
            const int gr = rowBase + sr;
            if constexpr (std::is_same<AT, float>::value) {
                float4 f0 = {0,0,0,0}, f1 = {0,0,0,0}, f2 = {0,0,0,0}, f3 = {0,0,0,0};
                if (gr < N) {
                    const float4* Ag = (const float4*)(A + (long)gr * K + k0 + seg);
                    f0 = Ag[0]; f1 = Ag[1]; f2 = Ag[2]; f3 = Ag[3];
                }
                bf16x8 p0, p1;
                p0[0] = (bf16)f0.x; p0[1] = (bf16)f0.y; p0[2] = (bf16)f0.z; p0[3] = (bf16)f0.w;
                p0[4] = (bf16)f1.x; p0[5] = (bf16)f1.y; p0[6] = (bf16)f1.z; p0[7] = (bf16)f1.w;
                p1[0] = (bf16)f2.x; p1[1] = (bf16)f2.y; p1[2] = (bf16)f2.z; p1[3] = (bf16)f2.w;
                p1[4] = (bf16)f3.x; p1[5] = (bf16)f3.y; p1[6] = (bf16)f3.z; p1[7] = (bf16)f3.w;
                *(bf16x8*)&As[sr * LDA + seg] = p0;
                *(bf16x8*)&As[sr * LDA + seg + 8] = p1;
            } else {
                bf16x8 p0 = {}, p1 = {};
                if (gr < N) {
                    const bf16x8* Ag = (const bf16x8*)(A + (long)gr * K + k0 + seg);
                    p0 = Ag[0]; p1 = Ag[1];
                }
                *(bf16x8*)&As[sr * LDA + seg] = p0;
                *(bf16x8*)&As[sr * LDA + seg + 8] = p1;
            }
        }
        {
            const bf16x8* Bg = (const bf16x8*)(Bt + (long)(colBase + sr) * K + k0 + seg);
            *(bf16x8*)&Bs[sr * LDA + seg] = Bg[0];
            *(bf16x8*)&Bs[sr * LDA + seg + 8] = Bg[1];
        }
        __syncthreads();

        bf16x8 af[4], bfr[4];
#pragma unroll
        for (int mi = 0; mi < 4; mi++)
            af[mi] = *(const bf16x8*)&As[(m_base + mi * 16 + l16) * LDA + quad * 8];
#pragma unroll
        for (int ni = 0; ni < 4; ni++)
            bfr[ni] = *(const bf16x8*)&Bs[(n_base + ni * 16 + l16) * LDA + quad * 8];
#pragma unroll
        for (int mi = 0; mi < 4; mi++)
#pragma unroll
            for (int ni = 0; ni < 4; ni++)
                acc[mi][ni] = __builtin_amdgcn_mfma_f32_16x16x32_bf16(af[mi], bfr[ni], acc[mi][ni], 0, 0, 0);
        __syncthreads();
    }

    // epilogue: C/D layout col=lane&15, row=quad*4+reg [m89-verified]; write bf16
#pragma unroll
    for (int mi = 0; mi < 4; mi++) {
#pragma unroll
        for (int r = 0; r < 4; r++) {
            const int grow = rowBase + m_base + mi * 16 + quad * 4 + r;
            if (grow < N) {
#pragma unroll
                for (int ni = 0; ni < 4; ni++) {
                    Fb[(long)grow * 256 + colBase + n_base + ni * 16 + l16] = (bf16)acc[mi][ni][r];
                }
            }
        }
    }

    // fused el/er + elmax: this wave's cols = head h, within-head col = ni*16+l16
    {
        const int h = (colBase >> 6) + (wave & 1);
        float alv[4], arv[4];
#pragma unroll
        for (int ni = 0; ni < 4; ni++) {
            alv[ni] = al[h * 64 + ni * 16 + l16];
            arv[ni] = ar[h * 64 + ni * 16 + l16];
        }
        float mxl = -INFINITY;
#pragma unroll
        for (int mi = 0; mi < 4; mi++) {
#pragma unroll
            for (int r = 0; r < 4; r++) {
                float sl = fmaf(acc[mi][0][r], alv[0], fmaf(acc[mi][1][r], alv[1],
                           fmaf(acc[mi][2][r], alv[2], acc[mi][3][r] * alv[3])));
                float sr2 = fmaf(acc[mi][0][r], arv[0], fmaf(acc[mi][1][r], arv[1],
                            fmaf(acc[mi][2][r], arv[2], acc[mi][3][r] * arv[3])));
#pragma unroll
                for (int off = 1; off < 16; off <<= 1) {
                    sl += __shfl_xor(sl, off);
                    sr2 += __shfl_xor(sr2, off);
                }
                const int grow = rowBase + m_base + mi * 16 + quad * 4 + r;
                if (l16 == 0 && grow < N) {
                    el[grow * 4 + h] = sl;
                    er[grow * 4 + h] = sr2;
                    mxl = fmaxf(mxl, sl);
                }
            }
        }
        if (l16 == 0) atomicMax(&elmax_u[h], f2s(mxl));
    }
}

// ---------------- MFMA GEMM narrow + fused layer-2 el/er/elmax -------------
// F2f[N,16] | F2r[N,16] = A[N,256](bf16) @ Bct^T. Feat waves (wave&1==0) also
// compute el2/er2 = F2f @ al2/ar2 from fp32 acc and atomicMax into elmax slot 8.
__global__ __launch_bounds__(256) void gemm_mfma_n32(const bf16* __restrict__ A,
                                                     const bf16* __restrict__ Bt,
                                                     float* __restrict__ F2f,
                                                     float* __restrict__ F2r,
                                                     const float* __restrict__ al2,
                                                     const float* __restrict__ ar2,
                                                     float* __restrict__ el,
                                                     float* __restrict__ er,
                                                     unsigned* __restrict__ elmax_u, int N) {
    constexpr int K = 256, BM = 128, BK = 32;
    constexpr int LDA = BK + 8;
    __shared__ bf16 As[BM * LDA];
    __shared__ bf16 Bs[32 * LDA];

    const int tid = threadIdx.x;
    const int wave = tid >> 6, lane = tid & 63;
    const int quad = lane >> 4, l16 = lane & 15;
    const int rowBase = blockIdx.x * BM;
    const int m_base = (wave >> 1) * 64, n_base = (wave & 1) * 16;

    f32x4 acc[4] = {};

    const int sr = tid >> 1;
    const int seg = (tid & 1) << 4;

    for (int k0 = 0; k0 < K; k0 += BK) {
        {
            const int gr = rowBase + sr;
            bf16x8 p0 = {}, p1 = {};
            if (gr < N) {
                const bf16x8* Ag = (const bf16x8*)(A + (long)gr * K + k0 + seg);
                p0 = Ag[0]; p1 = Ag[1];
            }
            *(bf16x8*)&As[sr * LDA + seg] = p0;
            *(bf16x8*)&As[sr * LDA + seg + 8] = p1;
        }
        if (tid < 64) {
            const int br = tid >> 1;
            const bf16x8* Bg = (const bf16x8*)(Bt + br * K + k0 + seg);
            *(bf16x8*)&Bs[br * LDA + seg] = Bg[0];
            *(bf16x8*)&Bs[br * LDA + seg + 8] = Bg[1];
        }
        __syncthreads();

        const bf16x8 bfr = *(const bf16x8*)&Bs[(n_base + l16) * LDA + quad * 8];
#pragma unroll
        for (int mi = 0; mi < 4; mi++) {
            const bf16x8 af = *(const bf16x8*)&As[(m_base + mi * 16 + l16) * LDA + quad * 8];
            acc[mi] = __builtin_amdgcn_mfma_f32_16x16x32_bf16(af, bfr, acc[mi], 0, 0, 0);
        }
        __syncthreads();
    }

    float* __restrict__ Cq = (wave & 1) ? F2r : F2f;
#pragma unroll
    for (int mi = 0; mi < 4; mi++) {
#pragma unroll
        for (int r = 0; r < 4; r++) {
            const int grow = rowBase + m_base + mi * 16 + quad * 4 + r;
            if (grow < N) Cq[(long)grow * 16 + l16] = acc[mi][r];
        }
    }

    if (!(wave & 1)) {  // feat waves hold all 16 cols (c = l16) of their rows
        const float alv = al2[l16], arv = ar2[l16];
        float mxl = -INFINITY;
#pragma unroll
        for (int mi = 0; mi < 4; mi++) {
#pragma unroll
            for (int r = 0; r < 4; r++) {
                float sl = acc[mi][r] * alv;
                float sr2 = acc[mi][r] * arv;
#pragma unroll
                for (int off = 1; off < 16; off <<= 1) {
                    sl += __shfl_xor(sl, off);
                    sr2 += __shfl_xor(sr2, off);
                }
                const int grow = rowBase + m_base + mi * 16 + quad * 4 + r;
                if (l16 == 0 && grow < N) {
                    el[grow] = sl;
                    er[grow] = sr2;
                    mxl = fmaxf(mxl, sl);
                }
            }
        }
        if (l16 == 0) atomicMax(&elmax_u[8], f2s(mxl));
    }
}

// ---------------- CSR build ----------------
// count_deg also records each edge's within-node position (atomic return value),
// which makes the scatter pass atomic-free.
__global__ void count_deg_kernel(const int* __restrict__ dst, int* __restrict__ deg,
                                 int* __restrict__ pos, int E) {
    const int e = blockIdx.x * blockDim.x + threadIdx.x;
    if (e >= E) return;
    pos[e] = atomicAdd(&deg[dst[e]], 1);
}

__global__ void scan_block_kernel(const int* __restrict__ deg, int* __restrict__ scanned,
                                  int* __restrict__ block_sums, int N) {
    __shared__ int smem[256];
    const int tid = threadIdx.x;
    const int base = blockIdx.x * 1024 + tid * 4;
    int v[4];
#pragma unroll
    for (int i = 0; i < 4; i++) v[i] = (base + i < N) ? deg[base + i] : 0;
    const int tsum = v[0] + v[1] + v[2] + v[3];
    smem[tid] = tsum;
    __syncthreads();
    int acc = tsum;
    for (int off = 1; off < 256; off <<= 1) {
        const int t = (tid >= off) ? smem[tid - off] : 0;
        __syncthreads();
        acc += t;
        smem[tid] = acc;
        __syncthreads();
    }
    if (tid == 255) block_sums[blockIdx.x] = acc;
    int run = acc - tsum;
#pragma unroll
    for (int i = 0; i < 4; i++) {
        if (base + i < N) scanned[base + i] = run;
        run += v[i];
    }
}

// single wave: exclusive-scan block sums; also inits the 12 elmax slots
__global__ void scan_sums_kernel(int* __restrict__ block_sums, unsigned* __restrict__ elmax_u, int nb) {
    const int tid = threadIdx.x;
    if (tid < 12) elmax_u[tid] = f2s(-INFINITY);
    const int orig = (tid < nb) ? block_sums[tid] : 0;
    int v = orig;
#pragma unroll
    for (int off = 1; off < 64; off <<= 1) {
        const int t = __shfl_up(v, off);
        if (tid >= off) v += t;
    }
    if (tid < nb) block_sums[tid] = v - orig;
}

__global__ void apply_offsets_kernel(const int* __restrict__ scanned, const int* __restrict__ block_sums,
                                     int* __restrict__ row_ptr, int N, int E) {
    const int i = blockIdx.x * blockDim.x + threadIdx.x;
    if (i < N) row_ptr[i] = scanned[i] + block_sums[i >> 10];
    if (i == 0) row_ptr[N] = E;
}

// atomic-free scatter: position precomputed in count pass
__global__ void scatter_kernel(const int* __restrict__ src, const int* __restrict__ dst,
                               const int* __restrict__ row_ptr, const int* __restrict__ pos,
                               int* __restrict__ csr_src, int E) {
    const int e = blockIdx.x * blockDim.x + threadIdx.x;
    if (e >= E) return;
    csr_src[row_ptr[dst[e]] + pos[e]] = src[e];
}

// ---------------- aggregate, split-wave: 2 edge slots x 32 lanes ----------------
// Wave = 1 node. Lanes 0-31 process even edge slot, 32-63 odd slot; each half-lane
// hl carries channels hl*8..hl*8+7 (bf16x8 = 16B), exactly one head (h = hl>>3).
// w = exp(leaky(el+erd) - sh) folded to exp2(max(fma(el,L,C1), fma(el,0.2L,C2))).
// ROOFLINE'd (r7): FETCH ~226MB = 8 XCD x 25.6MB feat compulsory traffic at
// ~3.8 TB/s fabric plateau; 8-edge MLP unroll was a measured null. Do not touch.
template <int H, int D, bool ACT, typename RT, typename OT>
__global__ void gat_aggregate_wave(const int* __restrict__ row_ptr, const int* __restrict__ csr_src,
                                   const float* __restrict__ el, const float* __restrict__ er,
                                   const unsigned* __restrict__ elmax_u,
                                   const bf16* __restrict__ feat,
                                   const RT* __restrict__ res, const float* __restrict__ bias,
                                   OT* __restrict__ out, int N) {
    static_assert(H == 4 && D == 64, "layout hardcoded for C=256");
    const int wave = threadIdx.x >> 6;
    const int lane = threadIdx.x & 63;
    int n = blockIdx.x * (blockDim.x >> 6) + wave;
    if (n >= N) return;
    n = __builtin_amdgcn_readfirstlane(n);
    const int sel = lane >> 5;       // edge slot
    const int hl = lane & 31;        // half-lane: channels hl*8..hl*8+7
    const int h = hl >> 3;           // head (8 lanes per head per half)

    const float erd = er[n * H + h];
    float sh = s2f(elmax_u[h]) + erd;
    sh = fmaxf(sh, 0.2f * sh);       // leaky(elmax + erd) >= e for all edges
    constexpr float L2E = 1.4426950408889634f;
    const float C1 = (erd - sh) * L2E;
    const float C2 = fmaf(0.2f, erd, -sh) * L2E;

    const char* csrB = (const char*)csr_src;
    const char* elB = (const char*)el;
    const char* featB = (const char*)feat;
    const unsigned hoff = (unsigned)(h << 2);    // el byte offset within node row
    const unsigned coff = (unsigned)(hl << 4);   // feat byte offset within row
    const unsigned selo = (unsigned)(sel << 2);  // csr byte offset of slot

    float acc[8] = {0.f, 0.f, 0.f, 0.f, 0.f, 0.f, 0.f, 0.f};
    float l = 0.f;
    int p = row_ptr[n];
    const int pend = row_ptr[n + 1];

#define CSRLD(PP) (*(const int*)(csrB + ((unsigned)((PP) << 2) + selo)))
#define ELLD(S)   (*(const float*)(elB + ((unsigned)((S) << 4) + hoff)))
#define FTLD(S)   (*(const bf16x8*)(featB + ((unsigned)((S) << 9) + coff)))
#define WCOMP(EV) __builtin_amdgcn_exp2f(fmaxf(fmaf((EV), L2E, C1), fmaf((EV), 0.2f * L2E, C2)))

    // 8 edges per iteration: 4 independent csr->gather chains in flight
    for (; p + 8 <= pend; p += 8) {
        const int sA = CSRLD(p);
        const int sB = CSRLD(p + 2);
        const int sC = CSRLD(p + 4);
        const int sD = CSRLD(p + 6);
        const float eA = ELLD(sA);
        const float eB = ELLD(sB);
        const float eC = ELLD(sC);
        const float eD = ELLD(sD);
        const bf16x8 fA = FTLD(sA);
        const bf16x8 fB = FTLD(sB);
        const bf16x8 fC = FTLD(sC);
        const bf16x8 fD = FTLD(sD);
        const float wA = WCOMP(eA);
        const float wB = WCOMP(eB);
        const float wC = WCOMP(eC);
        const float wD = WCOMP(eD);
        l += (wA + wB) + (wC + wD);
#pragma unroll
        for (int i = 0; i < 8; i++)
            acc[i] = fmaf(wA, (float)fA[i],
                     fmaf(wB, (float)fB[i],
                     fmaf(wC, (float)fC[i],
                     fmaf(wD, (float)fD[i], acc[i]))));
    }
    // 4-edge round
    for (; p + 4 <= pend; p += 4) {
        const int sA = CSRLD(p);
        const int sB = CSRLD(p + 2);
        const float eA = ELLD(sA);
        const float eB = ELLD(sB);
        const bf16x8 fA = FTLD(sA);
        const bf16x8 fB = FTLD(sB);
        const float wA = WCOMP(eA);
        const float wB = WCOMP(eB);
        l += wA + wB;
#pragma unroll
        for (int i = 0; i < 8; i++)
            acc[i] = fmaf(wA, (float)fA[i], fmaf(wB, (float)fB[i], acc[i]));
    }
    // 2-edge round
    for (; p + 2 <= pend; p += 2) {
        const int sA = CSRLD(p);
        const float eA = ELLD(sA);
        const bf16x8 fA = FTLD(sA);
        const float wA = WCOMP(eA);
        l += wA;
#pragma unroll
        for (int i = 0; i < 8; i++)
            acc[i] = fmaf(wA, (float)fA[i], acc[i]);
    }
    if (p < pend) {  // single remaining edge: upper half contributes zero weight
        const int s_ = *(const int*)(csrB + (unsigned)(p << 2));
        const float ev_ = ELLD(s_);
        float w_ = WCOMP(ev_);
        if (sel) w_ = 0.f;
        const bf16x8 f_ = FTLD(s_);
        l += w_;
#pragma unroll
        for (int i_ = 0; i_ < 8; i_++) acc[i_] = fmaf(w_, (float)f_[i_], acc[i_]);
    }
#undef CSRLD
#undef ELLD
#undef FTLD
#undef WCOMP

    // combine the two edge-slot halves (partner lane has same hl => same channels/head)
    l += __shfl_xor(l, 32);
#pragma unroll
    for (int i = 0; i < 8; i++) acc[i] += __shfl_xor(acc[i], 32);
    const float inv = (l > 0.f) ? __builtin_amdgcn_rcpf(l) : 0.f;

    // each lane finalizes 4 of its 8 channels: lower half i=0..3, upper half i=4..7
    const float a0 = (sel ? acc[4] : acc[0]) * inv;
    const float a1 = (sel ? acc[5] : acc[1]) * inv;
    const float a2 = (sel ? acc[6] : acc[2]) * inv;
    const float a3 = (sel ? acc[7] : acc[3]) * inv;
    const unsigned ib = (unsigned)(sel << 2);  // channel sub-offset 0 or 4

    float4 r;
    if constexpr (std::is_same<RT, float>::value) {
        r = *(const float4*)((const char*)res + ((size_t)n << 10) + (coff << 1) + (ib << 2));
    } else {
        const bf16x4 rb = *(const bf16x4*)((const char*)res + ((size_t)n << 9) + coff + (ib << 1));
        r = make_float4((float)rb[0], (float)rb[1], (float)rb[2], (float)rb[3]);
    }
    const float4 bb = *(const float4*)((const char*)bias + (coff << 1) + (ib << 2));
    float v0 = a0 + r.x + bb.x;
    float v1 = a1 + r.y + bb.y;
    float v2 = a2 + r.z + bb.z;
    float v3 = a3 + r.w + bb.w;
    if (ACT) {
        v0 = fast_mish(v0);
        v1 = fast_mish(v1);
        v2 = fast_mish(v2);
        v3 = fast_mish(v3);
    }
    if constexpr (std::is_same<OT, float>::value) {
        float4 o = {v0, v1, v2, v3};
        *(float4*)((char*)out + ((size_t)n << 10) + (coff << 1) + (ib << 2)) = o;
    } else {
        bf16x4 o;
        o[0] = (bf16)v0; o[1] = (bf16)v1; o[2] = (bf16)v2; o[3] = (bf16)v3;
        *(bf16x4*)((char*)out + ((size_t)n << 9) + coff + (ib << 1)) = o;
    }
}

// ---------------- layer-2 aggregate: wave per node, 4 edge slots x 16 channels ----
// F2f rows are 16 floats (64B, dense; 3.2MB total -> per-XCD-L2 resident).
// F2r holds the residual projection separately. 8 edges/iter for latency hiding.
__global__ void gat_aggregate_small16(const int* __restrict__ row_ptr, const int* __restrict__ csr_src,
                                      const float* __restrict__ el, const float* __restrict__ er,
                                      const unsigned* __restrict__ elmax_u,
                                      const float* __restrict__ F2f, const float* __restrict__ F2r,
                                      const float* __restrict__ bias,
                                      float* __restrict__ out, int N) {
    const int wave = threadIdx.x >> 6;
    const int lane = threadIdx.x & 63;
    int n = blockIdx.x * (blockDim.x >> 6) + wave;
    if (n >= N) return;
    n = __builtin_amdgcn_readfirstlane(n);
    const int slot = lane >> 4;
    const int c = lane & 15;

    const float mx = fmaxf(fmaxf(s2f(elmax_u[8]), s2f(elmax_u[9])),
                           fmaxf(s2f(elmax_u[10]), s2f(elmax_u[11])));
    const float erd = er[n];
    float sh = mx + erd;
    sh = fmaxf(sh, 0.2f * sh);
    constexpr float L2E = 1.4426950408889634f;
    const float C1 = (erd - sh) * L2E;
    const float C2 = fmaf(0.2f, erd, -sh) * L2E;

    const char* csrB = (const char*)csr_src;
    const char* elB = (const char*)el;
    const char* fB = (const char*)F2f;
    const unsigned co = (unsigned)(c << 2);
    const unsigned so = (unsigned)(slot << 2);

    float acc = 0.f, l = 0.f;
    int p = row_ptr[n];
    const int pend = row_ptr[n + 1];
    for (; p + 8 <= pend; p += 8) {
        const int s0 = *(const int*)(csrB + ((unsigned)(p << 2) + so));
        const int s1 = *(const int*)(csrB + ((unsigned)((p + 4) << 2) + so));
        const float e0 = *(const float*)(elB + (unsigned)(s0 << 2));
        const float e1 = *(const float*)(elB + (unsigned)(s1 << 2));
        const float f0 = *(const float*)(fB + ((unsigned)(s0 << 6) + co));
        const float f1 = *(const float*)(fB + ((unsigned)(s1 << 6) + co));
        const float w0 = __builtin_amdgcn_exp2f(
            fmaxf(fmaf(e0, L2E, C1), fmaf(e0, 0.2f * L2E, C2)));
        const float w1 = __builtin_amdgcn_exp2f(
            fmaxf(fmaf(e1, L2E, C1), fmaf(e1, 0.2f * L2E, C2)));
        l += w0 + w1;
        acc = fmaf(w0, f0, fmaf(w1, f1, acc));
    }
    for (; p + 4 <= pend; p += 4) {
        const int s_ = *(const int*)(csrB + ((unsigned)(p << 2) + so));
        const float ev_ = *(const float*)(elB + (unsigned)(s_ << 2));
        const float w_ = __builtin_amdgcn_exp2f(
            fmaxf(fmaf(ev_, L2E, C1), fmaf(ev_, 0.2f * L2E, C2)));
        const float f_ = *(const float*)(fB + ((unsigned)(s_ << 6) + co));
        l += w_;
        acc = fmaf(w_, f_, acc);
    }
    if (p < pend) {  // 1..3 remaining edges, masked by slot
        const int q = p + slot;
        const bool valid = q < pend;
        const int qi = valid ? q : p;
        const int s_ = *(const int*)(csrB + (unsigned)(qi << 2));
        const float ev_ = *(const float*)(elB + (unsigned)(s_ << 2));
        float w_ = __builtin_amdgcn_exp2f(
            fmaxf(fmaf(ev_, L2E, C1), fmaf(ev_, 0.2f * L2E, C2)));
        if (!valid) w_ = 0.f;
        const float f_ = *(const float*)(fB + ((unsigned)(s_ << 6) + co));
        l += w_;
        acc = fmaf(w_, f_, acc);
    }
    l += __shfl_xor(l, 16);
    l += __shfl_xor(l, 32);
    acc += __shfl_xor(acc, 16);
    acc += __shfl_xor(acc, 32);
    const float inv = (l > 0.f) ? __builtin_amdgcn_rcpf(l) : 0.f;
    if (lane < 16) {
        const float rv = F2r[(long)n * 16 + c];
        out[(long)n * 16 + c] = fmaf(acc, inv, rv + bias[c]);
    }
}

// ---------------- host orchestration ----------------

static inline int cdiv(long a, long b) { return (int)((a + b - 1) / b); }

extern "C" void kernel_launch(void* const* d_in, const int* in_sizes, int n_in,
                              void* d_out, int out_size, void* d_ws, size_t ws_size,
                              hipStream_t stream) {
    const float* x   = (const float*)d_in[0];
    const int*   src = (const int*)d_in[1];
    const int*   dst = (const int*)d_in[2];
    const float* W0  = (const float*)d_in[3];
    const float* al0 = (const float*)d_in[4];
    const float* ar0 = (const float*)d_in[5];
    const float* b0  = (const float*)d_in[6];
    const float* W1  = (const float*)d_in[7];
    const float* al1 = (const float*)d_in[8];
    const float* ar1 = (const float*)d_in[9];
    const float* b1  = (const float*)d_in[10];
    const float* W2  = (const float*)d_in[11];
    const float* al2 = (const float*)d_in[12];
    const float* ar2 = (const float*)d_in[13];
    const float* b2  = (const float*)d_in[14];
    const float* rW2 = (const float*)d_in[15];
    float* out = (float*)d_out;

    const int N = in_sizes[0] / 256;   // 50000
    const int E = in_sizes[1];         // 800000

    // workspace layout
    bf16* Wt0    = (bf16*)d_ws;               // 256*256 bf16
    bf16* Wt1    = Wt0 + 65536;               // 256*256 bf16
    bf16* Bct    = Wt1 + 65536;               // 32*256 bf16
    bf16* Fb     = Bct + 8192;                // N*256 bf16 feat
    bf16* Hb     = Fb + (long)N * 256;        // N*256 bf16 hidden
    float* F2f   = (float*)(Hb + (long)N * 256);  // N*16 (layer2 feat, dense)
    float* F2r   = F2f + (long)N * 16;        // N*16 (layer2 residual)
    float* el    = F2r + (long)N * 16;        // N*4
    float* er    = el + (long)N * 4;          // N*4
    unsigned* elmax_u = (unsigned*)(er + (long)N * 4); // 12
    int* deg     = (int*)(elmax_u + 12);      // N
    int* scanned = deg + N;                   // N
    int* bsums   = scanned + N;               // 64
    int* row_ptr = bsums + 64;                // N+1
    int* pos     = row_ptr + N + 1;           // E
    int* csr_src = pos + E;                   // E

    const int THREADS = 256;
    const int NB = cdiv(N, 1024);
    dim3 mfma_grid(2, cdiv(N, 128));

    // ---------- prep + CSR build (reused by all layers) ----------
    prep_weights_kernel<<<cdiv(65536, THREADS), THREADS, 0, stream>>>(W0, W1, W2, rW2, Wt0, Wt1, Bct);
    hipMemsetAsync(deg, 0, (size_t)N * 4, stream);
    count_deg_kernel<<<cdiv(E, THREADS), THREADS, 0, stream>>>(dst, deg, pos, E);
    scan_block_kernel<<<NB, 256, 0, stream>>>(deg, scanned, bsums, N);
    scan_sums_kernel<<<1, 64, 0, stream>>>(bsums, elmax_u, NB);
    apply_offsets_kernel<<<cdiv(N, THREADS), THREADS, 0, stream>>>(scanned, bsums, row_ptr, N, E);
    scatter_kernel<<<cdiv(E, THREADS), THREADS, 0, stream>>>(src, dst, row_ptr, pos, csr_src, E);

    // ================= Layer 0 (H=4, D=64), input x (fp32), out Hb (bf16) =========
    gemm_mfma_bf16<float><<<mfma_grid, 256, 0, stream>>>(x, Wt0, Fb, al0, ar0, el, er, elmax_u, N);
    gat_aggregate_wave<4, 64, true, float, bf16><<<cdiv(N, 4), 256, 0, stream>>>(
        row_ptr, csr_src, el, er, elmax_u, Fb, x, b0, Hb, N);

    // ================= Layer 1 (H=4, D=64), input Hb (bf16), in-place =============
    gemm_mfma_bf16<bf16><<<mfma_grid, 256, 0, stream>>>(Hb, Wt1, Fb, al1, ar1, el, er, elmax_u + 4, N);
    gat_aggregate_wave<4, 64, true, bf16, bf16><<<cdiv(N, 4), 256, 0, stream>>>(
        row_ptr, csr_src, el, er, elmax_u + 4, Fb, Hb, b1, Hb, N);

    // ================= Layer 2 (H=1, D=16): F2f|F2r = Hb @ [W2|rW2] ================
    gemm_mfma_n32<<<cdiv(N, 128), 256, 0, stream>>>(Hb, Bct, F2f, F2r, al2, ar2, el, er, elmax_u, N);
    gat_aggregate_small16<<<cdiv(N, 4), 256, 0, stream>>>(row_ptr, csr_src, el, er, elmax_u,
                                                          F2f, F2r, b2, out, N);
}

// Round 12
// 405.992 us; speedup vs baseline: 1.6204x; 1.6204x over previous
//
#include <hip/hip_runtime.h>
#include <cmath>
#include <type_traits>

typedef __bf16 bf16;
typedef __attribute__((ext_vector_type(8))) __bf16 bf16x8;
typedef __attribute__((ext_vector_type(4))) __bf16 bf16x4;
typedef __attribute__((ext_vector_type(4))) float f32x4;

__device__ __forceinline__ unsigned f2s(float x) {
    unsigned u = __float_as_uint(x);
    return (u & 0x80000000u) ? ~u : (u | 0x80000000u);
}
__device__ __forceinline__ float s2f(unsigned s) {
    return (s & 0x80000000u) ? __uint_as_float(s & 0x7FFFFFFFu)
                             : __uint_as_float(~s);
}

// mish(x) = x*tanh(softplus(x)) = x*(t^2+2t)/(t^2+2t+2), t=e^x (clamped; ratio->1)
__device__ __forceinline__ float fast_mish(float x) {
    const float t = __expf(fminf(x, 32.f));
    const float num = fmaf(t, t, t + t);   // (1+t)^2 - 1
    const float den = num + 2.f;           // (1+t)^2 + 1
    return x * num * __builtin_amdgcn_rcpf(den);
}

// ---------------- combined weight prep ----------------
__global__ void prep_weights_kernel(const float* __restrict__ W0, const float* __restrict__ W1,
                                    const float* __restrict__ W2, const float* __restrict__ rW2,
                                    bf16* __restrict__ Wt0, bf16* __restrict__ Wt1,
                                    bf16* __restrict__ Bct) {
    const int idx = blockIdx.x * blockDim.x + threadIdx.x;
    if (idx < 65536) {
        const int k = idx >> 8, m = idx & 255;
        Wt0[m * 256 + k] = (bf16)W0[idx];
        Wt1[m * 256 + k] = (bf16)W1[idx];
    }
    if (idx < 8192) {
        const int m = idx >> 8, k = idx & 255;
        const float v = (m < 16) ? W2[k * 16 + m] : rW2[k * 16 + (m - 16)];
        Bct[idx] = (bf16)v;
    }
}

// ---------------- MFMA GEMM + fused el/er epilogue (NO atomics) ----------------
// Fb[N,256](bf16) = A[N,256] @ Bt^T. Each wave's 64 output cols span one head
// h = 2*blockIdx.x + (wave&1). el/er from fp32 acc; per-block head-max written to
// blockmax[h*gridDim.y + blockIdx.y] via plain stores (r9 lesson: per-wave
// same-line atomicMax cost ~125us/dispatch -> zero-atomic scheme).
template <typename AT>
__global__ __launch_bounds__(256) void gemm_mfma_bf16(const AT* __restrict__ A,
                                                      const bf16* __restrict__ Bt,
                                                      bf16* __restrict__ Fb,
                                                      const float* __restrict__ al,
                                                      const float* __restrict__ ar,
                                                      float* __restrict__ el,
                                                      float* __restrict__ er,
                                                      float* __restrict__ blockmax, int N) {
    constexpr int K = 256, BM = 128, BK = 32;
    constexpr int LDA = BK + 8;
    __shared__ bf16 As[BM * LDA];
    __shared__ bf16 Bs[BM * LDA];
    __shared__ float smax[4];

    const int tid = threadIdx.x;
    const int wave = tid >> 6, lane = tid & 63;
    const int quad = lane >> 4, l16 = lane & 15;
    const int rowBase = blockIdx.y * BM;
    const int colBase = blockIdx.x * BM;
    const int m_base = (wave >> 1) * 64, n_base = (wave & 1) * 64;

    f32x4 acc[4][4] = {};

    const int sr = tid >> 1;
    const int seg = (tid & 1) << 4;

    for (int k0 = 0; k0 < K; k0 += BK) {
        {
            const int gr = rowBase + sr;
            if constexpr (std::is_same<AT, float>::value) {
                float4 f0 = {0,0,0,0}, f1 = {0,0,0,0}, f2 = {0,0,0,0}, f3 = {0,0,0,0};
                if (gr < N) {
                    const float4* Ag = (const float4*)(A + (long)gr * K + k0 + seg);
                    f0 = Ag[0]; f1 = Ag[1]; f2 = Ag[2]; f3 = Ag[3];
                }
                bf16x8 p0, p1;
                p0[0] = (bf16)f0.x; p0[1] = (bf16)f0.y; p0[2] = (bf16)f0.z; p0[3] = (bf16)f0.w;
                p0[4] = (bf16)f1.x; p0[5] = (bf16)f1.y; p0[6] = (bf16)f1.z; p0[7] = (bf16)f1.w;
                p1[0] = (bf16)f2.x; p1[1] = (bf16)f2.y; p1[2] = (bf16)f2.z; p1[3] = (bf16)f2.w;
                p1[4] = (bf16)f3.x; p1[5] = (bf16)f3.y; p1[6] = (bf16)f3.z; p1[7] = (bf16)f3.w;
                *(bf16x8*)&As[sr * LDA + seg] = p0;
                *(bf16x8*)&As[sr * LDA + seg + 8] = p1;
            } else {
                bf16x8 p0 = {}, p1 = {};
                if (gr < N) {
                    const bf16x8* Ag = (const bf16x8*)(A + (long)gr * K + k0 + seg);
                    p0 = Ag[0]; p1 = Ag[1];
                }
                *(bf16x8*)&As[sr * LDA + seg] = p0;
                *(bf16x8*)&As[sr * LDA + seg + 8] = p1;
            }
        }
        {
            const bf16x8* Bg = (const bf16x8*)(Bt + (long)(colBase + sr) * K + k0 + seg);
            *(bf16x8*)&Bs[sr * LDA + seg] = Bg[0];
            *(bf16x8*)&Bs[sr * LDA + seg + 8] = Bg[1];
        }
        __syncthreads();

        bf16x8 af[4], bfr[4];
#pragma unroll
        for (int mi = 0; mi < 4; mi++)
            af[mi] = *(const bf16x8*)&As[(m_base + mi * 16 + l16) * LDA + quad * 8];
#pragma unroll
        for (int ni = 0; ni < 4; ni++)
            bfr[ni] = *(const bf16x8*)&Bs[(n_base + ni * 16 + l16) * LDA + quad * 8];
#pragma unroll
        for (int mi = 0; mi < 4; mi++)
#pragma unroll
            for (int ni = 0; ni < 4; ni++)
                acc[mi][ni] = __builtin_amdgcn_mfma_f32_16x16x32_bf16(af[mi], bfr[ni], acc[mi][ni], 0, 0, 0);
        __syncthreads();
    }

    // epilogue: C/D layout col=lane&15, row=quad*4+reg [m89-verified]; write bf16
#pragma unroll
    for (int mi = 0; mi < 4; mi++) {
#pragma unroll
        for (int r = 0; r < 4; r++) {
            const int grow = rowBase + m_base + mi * 16 + quad * 4 + r;
            if (grow < N) {
#pragma unroll
                for (int ni = 0; ni < 4; ni++) {
                    Fb[(long)grow * 256 + colBase + n_base + ni * 16 + l16] = (bf16)acc[mi][ni][r];
                }
            }
        }
    }

    // fused el/er: this wave's cols = head h, within-head col = ni*16+l16
    {
        const int h = (colBase >> 6) + (wave & 1);
        float alv[4], arv[4];
#pragma unroll
        for (int ni = 0; ni < 4; ni++) {
            alv[ni] = al[h * 64 + ni * 16 + l16];
            arv[ni] = ar[h * 64 + ni * 16 + l16];
        }
        float mxl = -INFINITY;
#pragma unroll
        for (int mi = 0; mi < 4; mi++) {
#pragma unroll
            for (int r = 0; r < 4; r++) {
                float sl = fmaf(acc[mi][0][r], alv[0], fmaf(acc[mi][1][r], alv[1],
                           fmaf(acc[mi][2][r], alv[2], acc[mi][3][r] * alv[3])));
                float sr2 = fmaf(acc[mi][0][r], arv[0], fmaf(acc[mi][1][r], arv[1],
                            fmaf(acc[mi][2][r], arv[2], acc[mi][3][r] * arv[3])));
#pragma unroll
                for (int off = 1; off < 16; off <<= 1) {
                    sl += __shfl_xor(sl, off);
                    sr2 += __shfl_xor(sr2, off);
                }
                const int grow = rowBase + m_base + mi * 16 + quad * 4 + r;
                if (l16 == 0 && grow < N) {
                    el[grow * 4 + h] = sl;
                    er[grow * 4 + h] = sr2;
                }
                if (grow < N) mxl = fmaxf(mxl, sl);  // sl broadcast across quad
            }
        }
        // combine quads -> wave max (lanes differ in bits 4,5)
        mxl = fmaxf(mxl, __shfl_xor(mxl, 16));
        mxl = fmaxf(mxl, __shfl_xor(mxl, 32));
        if (lane == 0) smax[wave] = mxl;
        __syncthreads();
        // waves {0,2} share h0 = colBase>>6; waves {1,3} share h0+1
        if (lane == 0 && wave < 2) {
            const int hh = (colBase >> 6) + wave;
            blockmax[hh * gridDim.y + blockIdx.y] = fmaxf(smax[wave], smax[wave + 2]);
        }
    }
}

// ---------------- MFMA GEMM narrow + fused layer-2 el/er (NO atomics) -------
// F2f[N,16] | F2r[N,16] = A[N,256](bf16) @ Bct^T. Feat waves (0,2) also compute
// el2/er2 from fp32 acc; per-block max -> blockmax[blockIdx.x] (plain store).
__global__ __launch_bounds__(256) void gemm_mfma_n32(const bf16* __restrict__ A,
                                                     const bf16* __restrict__ Bt,
                                                     float* __restrict__ F2f,
                                                     float* __restrict__ F2r,
                                                     const float* __restrict__ al2,
                                                     const float* __restrict__ ar2,
                                                     float* __restrict__ el,
                                                     float* __restrict__ er,
                                                     float* __restrict__ blockmax, int N) {
    constexpr int K = 256, BM = 128, BK = 32;
    constexpr int LDA = BK + 8;
    __shared__ bf16 As[BM * LDA];
    __shared__ bf16 Bs[32 * LDA];
    __shared__ float smax[4];

    const int tid = threadIdx.x;
    const int wave = tid >> 6, lane = tid & 63;
    const int quad = lane >> 4, l16 = lane & 15;
    const int rowBase = blockIdx.x * BM;
    const int m_base = (wave >> 1) * 64, n_base = (wave & 1) * 16;

    f32x4 acc[4] = {};

    const int sr = tid >> 1;
    const int seg = (tid & 1) << 4;

    for (int k0 = 0; k0 < K; k0 += BK) {
        {
            const int gr = rowBase + sr;
            bf16x8 p0 = {}, p1 = {};
            if (gr < N) {
                const bf16x8* Ag = (const bf16x8*)(A + (long)gr * K + k0 + seg);
                p0 = Ag[0]; p1 = Ag[1];
            }
            *(bf16x8*)&As[sr * LDA + seg] = p0;
            *(bf16x8*)&As[sr * LDA + seg + 8] = p1;
        }
        if (tid < 64) {
            const int br = tid >> 1;
            const bf16x8* Bg = (const bf16x8*)(Bt + br * K + k0 + seg);
            *(bf16x8*)&Bs[br * LDA + seg] = Bg[0];
            *(bf16x8*)&Bs[br * LDA + seg + 8] = Bg[1];
        }
        __syncthreads();

        const bf16x8 bfr = *(const bf16x8*)&Bs[(n_base + l16) * LDA + quad * 8];
#pragma unroll
        for (int mi = 0; mi < 4; mi++) {
            const bf16x8 af = *(const bf16x8*)&As[(m_base + mi * 16 + l16) * LDA + quad * 8];
            acc[mi] = __builtin_amdgcn_mfma_f32_16x16x32_bf16(af, bfr, acc[mi], 0, 0, 0);
        }
        __syncthreads();
    }

    float* __restrict__ Cq = (wave & 1) ? F2r : F2f;
#pragma unroll
    for (int mi = 0; mi < 4; mi++) {
#pragma unroll
        for (int r = 0; r < 4; r++) {
            const int grow = rowBase + m_base + mi * 16 + quad * 4 + r;
            if (grow < N) Cq[(long)grow * 16 + l16] = acc[mi][r];
        }
    }

    float mxl = -INFINITY;
    if (!(wave & 1)) {  // feat waves hold all 16 cols (c = l16) of their rows
        const float alv = al2[l16], arv = ar2[l16];
#pragma unroll
        for (int mi = 0; mi < 4; mi++) {
#pragma unroll
            for (int r = 0; r < 4; r++) {
                float sl = acc[mi][r] * alv;
                float sr2 = acc[mi][r] * arv;
#pragma unroll
                for (int off = 1; off < 16; off <<= 1) {
                    sl += __shfl_xor(sl, off);
                    sr2 += __shfl_xor(sr2, off);
                }
                const int grow = rowBase + m_base + mi * 16 + quad * 4 + r;
                if (l16 == 0 && grow < N) {
                    el[grow] = sl;
                    er[grow] = sr2;
                }
                if (grow < N) mxl = fmaxf(mxl, sl);
            }
        }
    }
    mxl = fmaxf(mxl, __shfl_xor(mxl, 16));
    mxl = fmaxf(mxl, __shfl_xor(mxl, 32));
    if (lane == 0) smax[wave] = mxl;
    __syncthreads();
    if (tid == 0) blockmax[blockIdx.x] = fmaxf(smax[0], smax[2]);
}

// ---------------- tiny blockmax reduce: 1 block, wave w = head w ----------------
__global__ void reduce_blockmax_kernel(const float* __restrict__ bm, int cnt, int nheads,
                                       unsigned* __restrict__ elmax_dst) {
    const int w = threadIdx.x >> 6;
    const int lane = threadIdx.x & 63;
    if (w >= nheads) return;
    float m = -INFINITY;
    for (int i = lane; i < cnt; i += 64) m = fmaxf(m, bm[w * cnt + i]);
#pragma unroll
    for (int off = 1; off < 64; off <<= 1) m = fmaxf(m, __shfl_xor(m, off));
    if (lane == 0) elmax_dst[w] = f2s(m);
}

// ---------------- CSR build ----------------
// count_deg also records each edge's within-node position (atomic return value),
// which makes the scatter pass atomic-free.
__global__ void count_deg_kernel(const int* __restrict__ dst, int* __restrict__ deg,
                                 int* __restrict__ pos, int E) {
    const int e = blockIdx.x * blockDim.x + threadIdx.x;
    if (e >= E) return;
    pos[e] = atomicAdd(&deg[dst[e]], 1);
}

__global__ void scan_block_kernel(const int* __restrict__ deg, int* __restrict__ scanned,
                                  int* __restrict__ block_sums, int N) {
    __shared__ int smem[256];
    const int tid = threadIdx.x;
    const int base = blockIdx.x * 1024 + tid * 4;
    int v[4];
#pragma unroll
    for (int i = 0; i < 4; i++) v[i] = (base + i < N) ? deg[base + i] : 0;
    const int tsum = v[0] + v[1] + v[2] + v[3];
    smem[tid] = tsum;
    __syncthreads();
    int acc = tsum;
    for (int off = 1; off < 256; off <<= 1) {
        const int t = (tid >= off) ? smem[tid - off] : 0;
        __syncthreads();
        acc += t;
        smem[tid] = acc;
        __syncthreads();
    }
    if (tid == 255) block_sums[blockIdx.x] = acc;
    int run = acc - tsum;
#pragma unroll
    for (int i = 0; i < 4; i++) {
        if (base + i < N) scanned[base + i] = run;
        run += v[i];
    }
}

// single wave: exclusive-scan block sums; also inits the 12 elmax slots
__global__ void scan_sums_kernel(int* __restrict__ block_sums, unsigned* __restrict__ elmax_u, int nb) {
    const int tid = threadIdx.x;
    if (tid < 12) elmax_u[tid] = f2s(-INFINITY);
    const int orig = (tid < nb) ? block_sums[tid] : 0;
    int v = orig;
#pragma unroll
    for (int off = 1; off < 64; off <<= 1) {
        const int t = __shfl_up(v, off);
        if (tid >= off) v += t;
    }
    if (tid < nb) block_sums[tid] = v - orig;
}

__global__ void apply_offsets_kernel(const int* __restrict__ scanned, const int* __restrict__ block_sums,
                                     int* __restrict__ row_ptr, int N, int E) {
    const int i = blockIdx.x * blockDim.x + threadIdx.x;
    if (i < N) row_ptr[i] = scanned[i] + block_sums[i >> 10];
    if (i == 0) row_ptr[N] = E;
}

// atomic-free scatter: position precomputed in count pass
__global__ void scatter_kernel(const int* __restrict__ src, const int* __restrict__ dst,
                               const int* __restrict__ row_ptr, const int* __restrict__ pos,
                               int* __restrict__ csr_src, int E) {
    const int e = blockIdx.x * blockDim.x + threadIdx.x;
    if (e >= E) return;
    csr_src[row_ptr[dst[e]] + pos[e]] = src[e];
}

// ---------------- aggregate, split-wave: 2 edge slots x 32 lanes ----------------
// ROOFLINE'd (r7): FETCH ~226MB = 8 XCD x 25.6MB feat compulsory traffic at
// ~3.8 TB/s fabric plateau; 8-edge MLP unroll was a measured null. Do not touch.
template <int H, int D, bool ACT, typename RT, typename OT>
__global__ void gat_aggregate_wave(const int* __restrict__ row_ptr, const int* __restrict__ csr_src,
                                   const float* __restrict__ el, const float* __restrict__ er,
                                   const unsigned* __restrict__ elmax_u,
                                   const bf16* __restrict__ feat,
                                   const RT* __restrict__ res, const float* __restrict__ bias,
                                   OT* __restrict__ out, int N) {
    static_assert(H == 4 && D == 64, "layout hardcoded for C=256");
    const int wave = threadIdx.x >> 6;
    const int lane = threadIdx.x & 63;
    int n = blockIdx.x * (blockDim.x >> 6) + wave;
    if (n >= N) return;
    n = __builtin_amdgcn_readfirstlane(n);
    const int sel = lane >> 5;       // edge slot
    const int hl = lane & 31;        // half-lane: channels hl*8..hl*8+7
    const int h = hl >> 3;           // head (8 lanes per head per half)

    const float erd = er[n * H + h];
    float sh = s2f(elmax_u[h]) + erd;
    sh = fmaxf(sh, 0.2f * sh);       // leaky(elmax + erd) >= e for all edges
    constexpr float L2E = 1.4426950408889634f;
    const float C1 = (erd - sh) * L2E;
    const float C2 = fmaf(0.2f, erd, -sh) * L2E;

    const char* csrB = (const char*)csr_src;
    const char* elB = (const char*)el;
    const char* featB = (const char*)feat;
    const unsigned hoff = (unsigned)(h << 2);    // el byte offset within node row
    const unsigned coff = (unsigned)(hl << 4);   // feat byte offset within row
    const unsigned selo = (unsigned)(sel << 2);  // csr byte offset of slot

    float acc[8] = {0.f, 0.f, 0.f, 0.f, 0.f, 0.f, 0.f, 0.f};
    float l = 0.f;
    int p = row_ptr[n];
    const int pend = row_ptr[n + 1];

#define CSRLD(PP) (*(const int*)(csrB + ((unsigned)((PP) << 2) + selo)))
#define ELLD(S)   (*(const float*)(elB + ((unsigned)((S) << 4) + hoff)))
#define FTLD(S)   (*(const bf16x8*)(featB + ((unsigned)((S) << 9) + coff)))
#define WCOMP(EV) __builtin_amdgcn_exp2f(fmaxf(fmaf((EV), L2E, C1), fmaf((EV), 0.2f * L2E, C2)))

    // 8 edges per iteration: 4 independent csr->gather chains in flight
    for (; p + 8 <= pend; p += 8) {
        const int sA = CSRLD(p);
        const int sB = CSRLD(p + 2);
        const int sC = CSRLD(p + 4);
        const int sD = CSRLD(p + 6);
        const float eA = ELLD(sA);
        const float eB = ELLD(sB);
        const float eC = ELLD(sC);
        const float eD = ELLD(sD);
        const bf16x8 fA = FTLD(sA);
        const bf16x8 fB = FTLD(sB);
        const bf16x8 fC = FTLD(sC);
        const bf16x8 fD = FTLD(sD);
        const float wA = WCOMP(eA);
        const float wB = WCOMP(eB);
        const float wC = WCOMP(eC);
        const float wD = WCOMP(eD);
        l += (wA + wB) + (wC + wD);
#pragma unroll
        for (int i = 0; i < 8; i++)
            acc[i] = fmaf(wA, (float)fA[i],
                     fmaf(wB, (float)fB[i],
                     fmaf(wC, (float)fC[i],
                     fmaf(wD, (float)fD[i], acc[i]))));
    }
    // 4-edge round
    for (; p + 4 <= pend; p += 4) {
        const int sA = CSRLD(p);
        const int sB = CSRLD(p + 2);
        const float eA = ELLD(sA);
        const float eB = ELLD(sB);
        const bf16x8 fA = FTLD(sA);
        const bf16x8 fB = FTLD(sB);
        const float wA = WCOMP(eA);
        const float wB = WCOMP(eB);
        l += wA + wB;
#pragma unroll
        for (int i = 0; i < 8; i++)
            acc[i] = fmaf(wA, (float)fA[i], fmaf(wB, (float)fB[i], acc[i]));
    }
    // 2-edge round
    for (; p + 2 <= pend; p += 2) {
        const int sA = CSRLD(p);
        const float eA = ELLD(sA);
        const bf16x8 fA = FTLD(sA);
        const float wA = WCOMP(eA);
        l += wA;
#pragma unroll
        for (int i = 0; i < 8; i++)
            acc[i] = fmaf(wA, (float)fA[i], acc[i]);
    }
    if (p < pend) {  // single remaining edge: upper half contributes zero weight
        const int s_ = *(const int*)(csrB + (unsigned)(p << 2));
        const float ev_ = ELLD(s_);
        float w_ = WCOMP(ev_);
        if (sel) w_ = 0.f;
        const bf16x8 f_ = FTLD(s_);
        l += w_;
#pragma unroll
        for (int i_ = 0; i_ < 8; i_++) acc[i_] = fmaf(w_, (float)f_[i_], acc[i_]);
    }
#undef CSRLD
#undef ELLD
#undef FTLD
#undef WCOMP

    // combine the two edge-slot halves (partner lane has same hl => same channels/head)
    l += __shfl_xor(l, 32);
#pragma unroll
    for (int i = 0; i < 8; i++) acc[i] += __shfl_xor(acc[i], 32);
    const float inv = (l > 0.f) ? __builtin_amdgcn_rcpf(l) : 0.f;

    // each lane finalizes 4 of its 8 channels: lower half i=0..3, upper half i=4..7
    const float a0 = (sel ? acc[4] : acc[0]) * inv;
    const float a1 = (sel ? acc[5] : acc[1]) * inv;
    const float a2 = (sel ? acc[6] : acc[2]) * inv;
    const float a3 = (sel ? acc[7] : acc[3]) * inv;
    const unsigned ib = (unsigned)(sel << 2);  // channel sub-offset 0 or 4

    float4 r;
    if constexpr (std::is_same<RT, float>::value) {
        r = *(const float4*)((const char*)res + ((size_t)n << 10) + (coff << 1) + (ib << 2));
    } else {
        const bf16x4 rb = *(const bf16x4*)((const char*)res + ((size_t)n << 9) + coff + (ib << 1));
        r = make_float4((float)rb[0], (float)rb[1], (float)rb[2], (float)rb[3]);
    }
    const float4 bb = *(const float4*)((const char*)bias + (coff << 1) + (ib << 2));
    float v0 = a0 + r.x + bb.x;
    float v1 = a1 + r.y + bb.y;
    float v2 = a2 + r.z + bb.z;
    float v3 = a3 + r.w + bb.w;
    if (ACT) {
        v0 = fast_mish(v0);
        v1 = fast_mish(v1);
        v2 = fast_mish(v2);
        v3 = fast_mish(v3);
    }
    if constexpr (std::is_same<OT, float>::value) {
        float4 o = {v0, v1, v2, v3};
        *(float4*)((char*)out + ((size_t)n << 10) + (coff << 1) + (ib << 2)) = o;
    } else {
        bf16x4 o;
        o[0] = (bf16)v0; o[1] = (bf16)v1; o[2] = (bf16)v2; o[3] = (bf16)v3;
        *(bf16x4*)((char*)out + ((size_t)n << 9) + coff + (ib << 1)) = o;
    }
}

// ---------------- layer-2 aggregate: wave per node, 4 edge slots x 16 channels ----
// F2f rows are 16 floats (64B, dense; 3.2MB total -> per-XCD-L2 resident).
// F2r holds the residual projection separately. 8 edges/iter for latency hiding.
__global__ void gat_aggregate_small16(const int* __restrict__ row_ptr, const int* __restrict__ csr_src,
                                      const float* __restrict__ el, const float* __restrict__ er,
                                      const unsigned* __restrict__ elmax_u,
                                      const float* __restrict__ F2f, const float* __restrict__ F2r,
                                      const float* __restrict__ bias,
                                      float* __restrict__ out, int N) {
    const int wave = threadIdx.x >> 6;
    const int lane = threadIdx.x & 63;
    int n = blockIdx.x * (blockDim.x >> 6) + wave;
    if (n >= N) return;
    n = __builtin_amdgcn_readfirstlane(n);
    const int slot = lane >> 4;
    const int c = lane & 15;

    const float mx = fmaxf(fmaxf(s2f(elmax_u[8]), s2f(elmax_u[9])),
                           fmaxf(s2f(elmax_u[10]), s2f(elmax_u[11])));
    const float erd = er[n];
    float sh = mx + erd;
    sh = fmaxf(sh, 0.2f * sh);
    constexpr float L2E = 1.4426950408889634f;
    const float C1 = (erd - sh) * L2E;
    const float C2 = fmaf(0.2f, erd, -sh) * L2E;

    const char* csrB = (const char*)csr_src;
    const char* elB = (const char*)el;
    const char* fB = (const char*)F2f;
    const unsigned co = (unsigned)(c << 2);
    const unsigned so = (unsigned)(slot << 2);

    float acc = 0.f, l = 0.f;
    int p = row_ptr[n];
    const int pend = row_ptr[n + 1];
    for (; p + 8 <= pend; p += 8) {
        const int s0 = *(const int*)(csrB + ((unsigned)(p << 2) + so));
        const int s1 = *(const int*)(csrB + ((unsigned)((p + 4) << 2) + so));
        const float e0 = *(const float*)(elB + (unsigned)(s0 << 2));
        const float e1 = *(const float*)(elB + (unsigned)(s1 << 2));
        const float f0 = *(const float*)(fB + ((unsigned)(s0 << 6) + co));
        const float f1 = *(const float*)(fB + ((unsigned)(s1 << 6) + co));
        const float w0 = __builtin_amdgcn_exp2f(
            fmaxf(fmaf(e0, L2E, C1), fmaf(e0, 0.2f * L2E, C2)));
        const float w1 = __builtin_amdgcn_exp2f(
            fmaxf(fmaf(e1, L2E, C1), fmaf(e1, 0.2f * L2E, C2)));
        l += w0 + w1;
        acc = fmaf(w0, f0, fmaf(w1, f1, acc));
    }
    for (; p + 4 <= pend; p += 4) {
        const int s_ = *(const int*)(csrB + ((unsigned)(p << 2) + so));
        const float ev_ = *(const float*)(elB + (unsigned)(s_ << 2));
        const float w_ = __builtin_amdgcn_exp2f(
            fmaxf(fmaf(ev_, L2E, C1), fmaf(ev_, 0.2f * L2E, C2)));
        const float f_ = *(const float*)(fB + ((unsigned)(s_ << 6) + co));
        l += w_;
        acc = fmaf(w_, f_, acc);
    }
    if (p < pend) {  // 1..3 remaining edges, masked by slot
        const int q = p + slot;
        const bool valid = q < pend;
        const int qi = valid ? q : p;
        const int s_ = *(const int*)(csrB + (unsigned)(qi << 2));
        const float ev_ = *(const float*)(elB + (unsigned)(s_ << 2));
        float w_ = __builtin_amdgcn_exp2f(
            fmaxf(fmaf(ev_, L2E, C1), fmaf(ev_, 0.2f * L2E, C2)));
        if (!valid) w_ = 0.f;
        const float f_ = *(const float*)(fB + ((unsigned)(s_ << 6) + co));
        l += w_;
        acc = fmaf(w_, f_, acc);
    }
    l += __shfl_xor(l, 16);
    l += __shfl_xor(l, 32);
    acc += __shfl_xor(acc, 16);
    acc += __shfl_xor(acc, 32);
    const float inv = (l > 0.f) ? __builtin_amdgcn_rcpf(l) : 0.f;
    if (lane < 16) {
        const float rv = F2r[(long)n * 16 + c];
        out[(long)n * 16 + c] = fmaf(acc, inv, rv + bias[c]);
    }
}

// ---------------- host orchestration ----------------

static inline int cdiv(long a, long b) { return (int)((a + b - 1) / b); }

extern "C" void kernel_launch(void* const* d_in, const int* in_sizes, int n_in,
                              void* d_out, int out_size, void* d_ws, size_t ws_size,
                              hipStream_t stream) {
    const float* x   = (const float*)d_in[0];
    const int*   src = (const int*)d_in[1];
    const int*   dst = (const int*)d_in[2];
    const float* W0  = (const float*)d_in[3];
    const float* al0 = (const float*)d_in[4];
    const float* ar0 = (const float*)d_in[5];
    const float* b0  = (const float*)d_in[6];
    const float* W1  = (const float*)d_in[7];
    const float* al1 = (const float*)d_in[8];
    const float* ar1 = (const float*)d_in[9];
    const float* b1  = (const float*)d_in[10];
    const float* W2  = (const float*)d_in[11];
    const float* al2 = (const float*)d_in[12];
    const float* ar2 = (const float*)d_in[13];
    const float* b2  = (const float*)d_in[14];
    const float* rW2 = (const float*)d_in[15];
    float* out = (float*)d_out;

    const int N = in_sizes[0] / 256;   // 50000
    const int E = in_sizes[1];         // 800000

    // workspace layout
    bf16* Wt0    = (bf16*)d_ws;               // 256*256 bf16
    bf16* Wt1    = Wt0 + 65536;               // 256*256 bf16
    bf16* Bct    = Wt1 + 65536;               // 32*256 bf16
    bf16* Fb     = Bct + 8192;                // N*256 bf16 feat
    bf16* Hb     = Fb + (long)N * 256;        // N*256 bf16 hidden
    float* F2f   = (float*)(Hb + (long)N * 256);  // N*16 (layer2 feat, dense)
    float* F2r   = F2f + (long)N * 16;        // N*16 (layer2 residual)
    float* el    = F2r + (long)N * 16;        // N*4
    float* er    = el + (long)N * 4;          // N*4
    unsigned* elmax_u = (unsigned*)(er + (long)N * 4); // 12
    int* deg     = (int*)(elmax_u + 12);      // N
    int* scanned = deg + N;                   // N
    int* bsums   = scanned + N;               // 64
    int* row_ptr = bsums + 64;                // N+1
    int* pos     = row_ptr + N + 1;           // E
    int* csr_src = pos + E;                   // E
    float* bmax  = (float*)(csr_src + E);     // 4 * gridY floats (scratch)

    const int THREADS = 256;
    const int NB = cdiv(N, 1024);
    const int NBY = cdiv(N, 128);             // 391
    dim3 mfma_grid(2, NBY);

    // ---------- prep + CSR build (reused by all layers) ----------
    prep_weights_kernel<<<cdiv(65536, THREADS), THREADS, 0, stream>>>(W0, W1, W2, rW2, Wt0, Wt1, Bct);
    hipMemsetAsync(deg, 0, (size_t)N * 4, stream);
    count_deg_kernel<<<cdiv(E, THREADS), THREADS, 0, stream>>>(dst, deg, pos, E);
    scan_block_kernel<<<NB, 256, 0, stream>>>(deg, scanned, bsums, N);
    scan_sums_kernel<<<1, 64, 0, stream>>>(bsums, elmax_u, NB);
    apply_offsets_kernel<<<cdiv(N, THREADS), THREADS, 0, stream>>>(scanned, bsums, row_ptr, N, E);
    scatter_kernel<<<cdiv(E, THREADS), THREADS, 0, stream>>>(src, dst, row_ptr, pos, csr_src, E);

    // ================= Layer 0 (H=4, D=64), input x (fp32), out Hb (bf16) =========
    gemm_mfma_bf16<float><<<mfma_grid, 256, 0, stream>>>(x, Wt0, Fb, al0, ar0, el, er, bmax, N);
    reduce_blockmax_kernel<<<1, 256, 0, stream>>>(bmax, NBY, 4, elmax_u);
    gat_aggregate_wave<4, 64, true, float, bf16><<<cdiv(N, 4), 256, 0, stream>>>(
        row_ptr, csr_src, el, er, elmax_u, Fb, x, b0, Hb, N);

    // ================= Layer 1 (H=4, D=64), input Hb (bf16), in-place =============
    gemm_mfma_bf16<bf16><<<mfma_grid, 256, 0, stream>>>(Hb, Wt1, Fb, al1, ar1, el, er, bmax, N);
    reduce_blockmax_kernel<<<1, 256, 0, stream>>>(bmax, NBY, 4, elmax_u + 4);
    gat_aggregate_wave<4, 64, true, bf16, bf16><<<cdiv(N, 4), 256, 0, stream>>>(
        row_ptr, csr_src, el, er, elmax_u + 4, Fb, Hb, b1, Hb, N);

    // ================= Layer 2 (H=1, D=16): F2f|F2r = Hb @ [W2|rW2] ================
    gemm_mfma_n32<<<cdiv(N, 128), 256, 0, stream>>>(Hb, Bct, F2f, F2r, al2, ar2, el, er, bmax, N);
    reduce_blockmax_kernel<<<1, 64, 0, stream>>>(bmax, NBY, 1, elmax_u + 8);
    gat_aggregate_small16<<<cdiv(N, 4), 256, 0, stream>>>(row_ptr, csr_src, el, er, elmax_u,
                                                          F2f, F2r, b2, out, N);
}

// Round 14
// 390.041 us; speedup vs baseline: 1.6866x; 1.0409x over previous
//
#include <hip/hip_runtime.h>
#include <cmath>
#include <type_traits>

typedef __bf16 bf16;
typedef __attribute__((ext_vector_type(8))) __bf16 bf16x8;
typedef __attribute__((ext_vector_type(4))) __bf16 bf16x4;
typedef __attribute__((ext_vector_type(4))) float f32x4;

__device__ __forceinline__ unsigned f2s(float x) {
    unsigned u = __float_as_uint(x);
    return (u & 0x80000000u) ? ~u : (u | 0x80000000u);
}
__device__ __forceinline__ float s2f(unsigned s) {
    return (s & 0x80000000u) ? __uint_as_float(s & 0x7FFFFFFFu)
                             : __uint_as_float(~s);
}

// mish(x) = x*tanh(softplus(x)) = x*(t^2+2t)/(t^2+2t+2), t=e^x (clamped; ratio->1)
__device__ __forceinline__ float fast_mish(float x) {
    const float t = __expf(fminf(x, 32.f));
    const float num = fmaf(t, t, t + t);   // (1+t)^2 - 1
    const float den = num + 2.f;           // (1+t)^2 + 1
    return x * num * __builtin_amdgcn_rcpf(den);
}

// ---------------- combined weight prep (+ deg zeroing, saves a memset dispatch) ----
__global__ void prep_weights_kernel(const float* __restrict__ W0, const float* __restrict__ W1,
                                    const float* __restrict__ W2, const float* __restrict__ rW2,
                                    bf16* __restrict__ Wt0, bf16* __restrict__ Wt1,
                                    bf16* __restrict__ Bct, int* __restrict__ deg, int N) {
    const int idx = blockIdx.x * blockDim.x + threadIdx.x;
    if (idx < 65536) {
        const int k = idx >> 8, m = idx & 255;
        Wt0[m * 256 + k] = (bf16)W0[idx];
        Wt1[m * 256 + k] = (bf16)W1[idx];
    }
    if (idx < 8192) {
        const int m = idx >> 8, k = idx & 255;
        const float v = (m < 16) ? W2[k * 16 + m] : rW2[k * 16 + (m - 16)];
        Bct[idx] = (bf16)v;
    }
    if (idx < N) deg[idx] = 0;
}

// ---------------- MFMA GEMM BN=256 + fused el/er epilogue (NO atomics) ----------
// Fb[N,256](bf16) = A[N,256] @ Bt^T, ONE block per 128-row tile computes all 256
// output cols (8 waves: m_base=(w>>2)*64, n_base=(w&3)*64) -> A staged ONCE
// (r12 grid=(2,NBY) staged A twice). Wave's 64 cols = head h = wave&3.
// el/er from fp32 acc; per-block head-max -> blockmax[h*gridDim.x+bx] plain store
// (r9 lesson: same-line atomicMax cost ~125us/dispatch).
template <typename AT>
__global__ __launch_bounds__(512) void gemm_mfma_bf16(const AT* __restrict__ A,
                                                      const bf16* __restrict__ Bt,
                                                      bf16* __restrict__ Fb,
                                                      const float* __restrict__ al,
                                                      const float* __restrict__ ar,
                                                      float* __restrict__ el,
                                                      float* __restrict__ er,
                                                      float* __restrict__ blockmax, int N) {
    constexpr int K = 256, BM = 128, BN = 256, BK = 32;
    constexpr int LDA = BK + 8;
    __shared__ bf16 As[BM * LDA];
    __shared__ bf16 Bs[BN * LDA];
    __shared__ float smax[8];

    const int tid = threadIdx.x;
    const int wave = tid >> 6, lane = tid & 63;
    const int quad = lane >> 4, l16 = lane & 15;
    const int rowBase = blockIdx.x * BM;
    const int m_base = (wave >> 2) * 64, n_base = (wave & 3) * 64;

    f32x4 acc[4][4] = {};

    const int sr = tid >> 2;           // A stage row 0..127 (4 threads x 16B per 64B row)
    const int sg = (tid & 3) << 3;     // element offset {0,8,16,24}
    const int br = tid >> 1;           // B stage row 0..255 (2 threads x 32B per row)
    const int bg = (tid & 1) << 4;     // element offset {0,16}

    for (int k0 = 0; k0 < K; k0 += BK) {
        {
            const int gr = rowBase + sr;
            if constexpr (std::is_same<AT, float>::value) {
                float4 f0 = {0,0,0,0}, f1 = {0,0,0,0};
                if (gr < N) {
                    const float4* Ag = (const float4*)(A + (long)gr * K + k0 + sg);
                    f0 = Ag[0]; f1 = Ag[1];
                }
                bf16x8 p;
                p[0] = (bf16)f0.x; p[1] = (bf16)f0.y; p[2] = (bf16)f0.z; p[3] = (bf16)f0.w;
                p[4] = (bf16)f1.x; p[5] = (bf16)f1.y; p[6] = (bf16)f1.z; p[7] = (bf16)f1.w;
                *(bf16x8*)&As[sr * LDA + sg] = p;
            } else {
                bf16x8 p = {};
                if (gr < N) p = *(const bf16x8*)(A + (long)gr * K + k0 + sg);
                *(bf16x8*)&As[sr * LDA + sg] = p;
            }
        }
        {
            const bf16x8* Bg = (const bf16x8*)(Bt + (long)br * K + k0 + bg);
            *(bf16x8*)&Bs[br * LDA + bg] = Bg[0];
            *(bf16x8*)&Bs[br * LDA + bg + 8] = Bg[1];
        }
        __syncthreads();

        bf16x8 af[4], bfr[4];
#pragma unroll
        for (int mi = 0; mi < 4; mi++)
            af[mi] = *(const bf16x8*)&As[(m_base + mi * 16 + l16) * LDA + quad * 8];
#pragma unroll
        for (int ni = 0; ni < 4; ni++)
            bfr[ni] = *(const bf16x8*)&Bs[(n_base + ni * 16 + l16) * LDA + quad * 8];
#pragma unroll
        for (int mi = 0; mi < 4; mi++)
#pragma unroll
            for (int ni = 0; ni < 4; ni++)
                acc[mi][ni] = __builtin_amdgcn_mfma_f32_16x16x32_bf16(af[mi], bfr[ni], acc[mi][ni], 0, 0, 0);
        __syncthreads();
    }

    // epilogue: C/D layout col=lane&15, row=quad*4+reg [m89-verified]; write bf16
#pragma unroll
    for (int mi = 0; mi < 4; mi++) {
#pragma unroll
        for (int r = 0; r < 4; r++) {
            const int grow = rowBase + m_base + mi * 16 + quad * 4 + r;
            if (grow < N) {
#pragma unroll
                for (int ni = 0; ni < 4; ni++) {
                    Fb[(long)grow * 256 + n_base + ni * 16 + l16] = (bf16)acc[mi][ni][r];
                }
            }
        }
    }

    // fused el/er: this wave's 64 cols = head h = wave&3, within-head col = ni*16+l16
    {
        const int h = wave & 3;
        float alv[4], arv[4];
#pragma unroll
        for (int ni = 0; ni < 4; ni++) {
            alv[ni] = al[h * 64 + ni * 16 + l16];
            arv[ni] = ar[h * 64 + ni * 16 + l16];
        }
        float mxl = -INFINITY;
#pragma unroll
        for (int mi = 0; mi < 4; mi++) {
#pragma unroll
            for (int r = 0; r < 4; r++) {
                float sl = fmaf(acc[mi][0][r], alv[0], fmaf(acc[mi][1][r], alv[1],
                           fmaf(acc[mi][2][r], alv[2], acc[mi][3][r] * alv[3])));
                float sr2 = fmaf(acc[mi][0][r], arv[0], fmaf(acc[mi][1][r], arv[1],
                            fmaf(acc[mi][2][r], arv[2], acc[mi][3][r] * arv[3])));
#pragma unroll
                for (int off = 1; off < 16; off <<= 1) {
                    sl += __shfl_xor(sl, off);
                    sr2 += __shfl_xor(sr2, off);
                }
                const int grow = rowBase + m_base + mi * 16 + quad * 4 + r;
                if (l16 == 0 && grow < N) {
                    el[grow * 4 + h] = sl;
                    er[grow * 4 + h] = sr2;
                }
                if (grow < N) mxl = fmaxf(mxl, sl);  // sl broadcast across quad
            }
        }
        // combine quads -> wave max (lanes differ in bits 4,5)
        mxl = fmaxf(mxl, __shfl_xor(mxl, 16));
        mxl = fmaxf(mxl, __shfl_xor(mxl, 32));
        if (lane == 0) smax[wave] = mxl;
        __syncthreads();
        // head h: rows 0-63 from wave h, rows 64-127 from wave h+4
        if (lane == 0 && wave < 4) {
            blockmax[wave * gridDim.x + blockIdx.x] = fmaxf(smax[wave], smax[wave + 4]);
        }
    }
}

// ---------------- MFMA GEMM narrow + fused layer-2 el/er (NO atomics) -------
// F2f[N,16] | F2r[N,16] = A[N,256](bf16) @ Bct^T. Feat waves (0,2) also compute
// el2/er2 from fp32 acc; per-block max -> blockmax[blockIdx.x] (plain store).
__global__ __launch_bounds__(256) void gemm_mfma_n32(const bf16* __restrict__ A,
                                                     const bf16* __restrict__ Bt,
                                                     float* __restrict__ F2f,
                                                     float* __restrict__ F2r,
                                                     const float* __restrict__ al2,
                                                     const float* __restrict__ ar2,
                                                     float* __restrict__ el,
                                                     float* __restrict__ er,
                                                     float* __restrict__ blockmax, int N) {
    constexpr int K = 256, BM = 128, BK = 32;
    constexpr int LDA = BK + 8;
    __shared__ bf16 As[BM * LDA];
    __shared__ bf16 Bs[32 * LDA];
    __shared__ float smax[4];

    const int tid = threadIdx.x;
    const int wave = tid >> 6, lane = tid & 63;
    const int quad = lane >> 4, l16 = lane & 15;
    const int rowBase = blockIdx.x * BM;
    const int m_base = (wave >> 1) * 64, n_base = (wave & 1) * 16;

    f32x4 acc[4] = {};

    const int sr = tid >> 1;
    const int seg = (tid & 1) << 4;

    for (int k0 = 0; k0 < K; k0 += BK) {
        {
            const int gr = rowBase + sr;
            bf16x8 p0 = {}, p1 = {};
            if (gr < N) {
                const bf16x8* Ag = (const bf16x8*)(A + (long)gr * K + k0 + seg);
                p0 = Ag[0]; p1 = Ag[1];
            }
            *(bf16x8*)&As[sr * LDA + seg] = p0;
            *(bf16x8*)&As[sr * LDA + seg + 8] = p1;
        }
        if (tid < 64) {
            const int br = tid >> 1;
            const bf16x8* Bg = (const bf16x8*)(Bt + br * K + k0 + seg);
            *(bf16x8*)&Bs[br * LDA + seg] = Bg[0];
            *(bf16x8*)&Bs[br * LDA + seg + 8] = Bg[1];
        }
        __syncthreads();

        const bf16x8 bfr = *(const bf16x8*)&Bs[(n_base + l16) * LDA + quad * 8];
#pragma unroll
        for (int mi = 0; mi < 4; mi++) {
            const bf16x8 af = *(const bf16x8*)&As[(m_base + mi * 16 + l16) * LDA + quad * 8];
            acc[mi] = __builtin_amdgcn_mfma_f32_16x16x32_bf16(af, bfr, acc[mi], 0, 0, 0);
        }
        __syncthreads();
    }

    float* __restrict__ Cq = (wave & 1) ? F2r : F2f;
#pragma unroll
    for (int mi = 0; mi < 4; mi++) {
#pragma unroll
        for (int r = 0; r < 4; r++) {
            const int grow = rowBase + m_base + mi * 16 + quad * 4 + r;
            if (grow < N) Cq[(long)grow * 16 + l16] = acc[mi][r];
        }
    }

    float mxl = -INFINITY;
    if (!(wave & 1)) {  // feat waves hold all 16 cols (c = l16) of their rows
        const float alv = al2[l16], arv = ar2[l16];
#pragma unroll
        for (int mi = 0; mi < 4; mi++) {
#pragma unroll
            for (int r = 0; r < 4; r++) {
                float sl = acc[mi][r] * alv;
                float sr2 = acc[mi][r] * arv;
#pragma unroll
                for (int off = 1; off < 16; off <<= 1) {
                    sl += __shfl_xor(sl, off);
                    sr2 += __shfl_xor(sr2, off);
                }
                const int grow = rowBase + m_base + mi * 16 + quad * 4 + r;
                if (l16 == 0 && grow < N) {
                    el[grow] = sl;
                    er[grow] = sr2;
                }
                if (grow < N) mxl = fmaxf(mxl, sl);
            }
        }
    }
    mxl = fmaxf(mxl, __shfl_xor(mxl, 16));
    mxl = fmaxf(mxl, __shfl_xor(mxl, 32));
    if (lane == 0) smax[wave] = mxl;
    __syncthreads();
    if (tid == 0) blockmax[blockIdx.x] = fmaxf(smax[0], smax[2]);
}

// ---------------- tiny blockmax reduce: 1 block, wave w = head w ----------------
__global__ void reduce_blockmax_kernel(const float* __restrict__ bm, int cnt, int nheads,
                                       unsigned* __restrict__ elmax_dst) {
    const int w = threadIdx.x >> 6;
    const int lane = threadIdx.x & 63;
    if (w >= nheads) return;
    float m = -INFINITY;
    for (int i = lane; i < cnt; i += 64) m = fmaxf(m, bm[w * cnt + i]);
#pragma unroll
    for (int off = 1; off < 64; off <<= 1) m = fmaxf(m, __shfl_xor(m, off));
    if (lane == 0) elmax_dst[w] = f2s(m);
}

// ---------------- CSR build ----------------
// count_deg also records each edge's within-node position (atomic return value),
// which makes the scatter pass atomic-free.
__global__ void count_deg_kernel(const int* __restrict__ dst, int* __restrict__ deg,
                                 int* __restrict__ pos, int E) {
    const int e = blockIdx.x * blockDim.x + threadIdx.x;
    if (e >= E) return;
    pos[e] = atomicAdd(&deg[dst[e]], 1);
}

__global__ void scan_block_kernel(const int* __restrict__ deg, int* __restrict__ scanned,
                                  int* __restrict__ block_sums, int N) {
    __shared__ int smem[256];
    const int tid = threadIdx.x;
    const int base = blockIdx.x * 1024 + tid * 4;
    int v[4];
#pragma unroll
    for (int i = 0; i < 4; i++) v[i] = (base + i < N) ? deg[base + i] : 0;
    const int tsum = v[0] + v[1] + v[2] + v[3];
    smem[tid] = tsum;
    __syncthreads();
    int acc = tsum;
    for (int off = 1; off < 256; off <<= 1) {
        const int t = (tid >= off) ? smem[tid - off] : 0;
        __syncthreads();
        acc += t;
        smem[tid] = acc;
        __syncthreads();
    }
    if (tid == 255) block_sums[blockIdx.x] = acc;
    int run = acc - tsum;
#pragma unroll
    for (int i = 0; i < 4; i++) {
        if (base + i < N) scanned[base + i] = run;
        run += v[i];
    }
}

// single wave: exclusive-scan block sums; also inits the 12 elmax slots
__global__ void scan_sums_kernel(int* __restrict__ block_sums, unsigned* __restrict__ elmax_u, int nb) {
    const int tid = threadIdx.x;
    if (tid < 12) elmax_u[tid] = f2s(-INFINITY);
    const int orig = (tid < nb) ? block_sums[tid] : 0;
    int v = orig;
#pragma unroll
    for (int off = 1; off < 64; off <<= 1) {
        const int t = __shfl_up(v, off);
        if (tid >= off) v += t;
    }
    if (tid < nb) block_sums[tid] = v - orig;
}

__global__ void apply_offsets_kernel(const int* __restrict__ scanned, const int* __restrict__ block_sums,
                                     int* __restrict__ row_ptr, int N, int E) {
    const int i = blockIdx.x * blockDim.x + threadIdx.x;
    if (i < N) row_ptr[i] = scanned[i] + block_sums[i >> 10];
    if (i == 0) row_ptr[N] = E;
}

// atomic-free scatter: position precomputed in count pass
__global__ void scatter_kernel(const int* __restrict__ src, const int* __restrict__ dst,
                               const int* __restrict__ row_ptr, const int* __restrict__ pos,
                               int* __restrict__ csr_src, int E) {
    const int e = blockIdx.x * blockDim.x + threadIdx.x;
    if (e >= E) return;
    csr_src[row_ptr[dst[e]] + pos[e]] = src[e];
}

// ---------------- aggregate, split-wave: 2 edge slots x 32 lanes ----------------
// ROOFLINE'd (r7): FETCH ~226MB = 8 XCD x 25.6MB feat compulsory traffic at
// ~3.8 TB/s fabric plateau; 8-edge MLP unroll was a measured null. Do not touch.
template <int H, int D, bool ACT, typename RT, typename OT>
__global__ void gat_aggregate_wave(const int* __restrict__ row_ptr, const int* __restrict__ csr_src,
                                   const float* __restrict__ el, const float* __restrict__ er,
                                   const unsigned* __restrict__ elmax_u,
                                   const bf16* __restrict__ feat,
                                   const RT* __restrict__ res, const float* __restrict__ bias,
                                   OT* __restrict__ out, int N) {
    static_assert(H == 4 && D == 64, "layout hardcoded for C=256");
    const int wave = threadIdx.x >> 6;
    const int lane = threadIdx.x & 63;
    int n = blockIdx.x * (blockDim.x >> 6) + wave;
    if (n >= N) return;
    n = __builtin_amdgcn_readfirstlane(n);
    const int sel = lane >> 5;       // edge slot
    const int hl = lane & 31;        // half-lane: channels hl*8..hl*8+7
    const int h = hl >> 3;           // head (8 lanes per head per half)

    const float erd = er[n * H + h];
    float sh = s2f(elmax_u[h]) + erd;
    sh = fmaxf(sh, 0.2f * sh);       // leaky(elmax + erd) >= e for all edges
    constexpr float L2E = 1.4426950408889634f;
    const float C1 = (erd - sh) * L2E;
    const float C2 = fmaf(0.2f, erd, -sh) * L2E;

    const char* csrB = (const char*)csr_src;
    const char* elB = (const char*)el;
    const char* featB = (const char*)feat;
    const unsigned hoff = (unsigned)(h << 2);    // el byte offset within node row
    const unsigned coff = (unsigned)(hl << 4);   // feat byte offset within row
    const unsigned selo = (unsigned)(sel << 2);  // csr byte offset of slot

    float acc[8] = {0.f, 0.f, 0.f, 0.f, 0.f, 0.f, 0.f, 0.f};
    float l = 0.f;
    int p = row_ptr[n];
    const int pend = row_ptr[n + 1];

#define CSRLD(PP) (*(const int*)(csrB + ((unsigned)((PP) << 2) + selo)))
#define ELLD(S)   (*(const float*)(elB + ((unsigned)((S) << 4) + hoff)))
#define FTLD(S)   (*(const bf16x8*)(featB + ((unsigned)((S) << 9) + coff)))
#define WCOMP(EV) __builtin_amdgcn_exp2f(fmaxf(fmaf((EV), L2E, C1), fmaf((EV), 0.2f * L2E, C2)))

    // 8 edges per iteration: 4 independent csr->gather chains in flight
    for (; p + 8 <= pend; p += 8) {
        const int sA = CSRLD(p);
        const int sB = CSRLD(p + 2);
        const int sC = CSRLD(p + 4);
        const int sD = CSRLD(p + 6);
        const float eA = ELLD(sA);
        const float eB = ELLD(sB);
        const float eC = ELLD(sC);
        const float eD = ELLD(sD);
        const bf16x8 fA = FTLD(sA);
        const bf16x8 fB = FTLD(sB);
        const bf16x8 fC = FTLD(sC);
        const bf16x8 fD = FTLD(sD);
        const float wA = WCOMP(eA);
        const float wB = WCOMP(eB);
        const float wC = WCOMP(eC);
        const float wD = WCOMP(eD);
        l += (wA + wB) + (wC + wD);
#pragma unroll
        for (int i = 0; i < 8; i++)
            acc[i] = fmaf(wA, (float)fA[i],
                     fmaf(wB, (float)fB[i],
                     fmaf(wC, (float)fC[i],
                     fmaf(wD, (float)fD[i], acc[i]))));
    }
    // 4-edge round
    for (; p + 4 <= pend; p += 4) {
        const int sA = CSRLD(p);
        const int sB = CSRLD(p + 2);
        const float eA = ELLD(sA);
        const float eB = ELLD(sB);
        const bf16x8 fA = FTLD(sA);
        const bf16x8 fB = FTLD(sB);
        const float wA = WCOMP(eA);
        const float wB = WCOMP(eB);
        l += wA + wB;
#pragma unroll
        for (int i = 0; i < 8; i++)
            acc[i] = fmaf(wA, (float)fA[i], fmaf(wB, (float)fB[i], acc[i]));
    }
    // 2-edge round
    for (; p + 2 <= pend; p += 2) {
        const int sA = CSRLD(p);
        const float eA = ELLD(sA);
        const bf16x8 fA = FTLD(sA);
        const float wA = WCOMP(eA);
        l += wA;
#pragma unroll
        for (int i = 0; i < 8; i++)
            acc[i] = fmaf(wA, (float)fA[i], acc[i]);
    }
    if (p < pend) {  // single remaining edge: upper half contributes zero weight
        const int s_ = *(const int*)(csrB + (unsigned)(p << 2));
        const float ev_ = ELLD(s_);
        float w_ = WCOMP(ev_);
        if (sel) w_ = 0.f;
        const bf16x8 f_ = FTLD(s_);
        l += w_;
#pragma unroll
        for (int i_ = 0; i_ < 8; i_++) acc[i_] = fmaf(w_, (float)f_[i_], acc[i_]);
    }
#undef CSRLD
#undef ELLD
#undef FTLD
#undef WCOMP

    // combine the two edge-slot halves (partner lane has same hl => same channels/head)
    l += __shfl_xor(l, 32);
#pragma unroll
    for (int i = 0; i < 8; i++) acc[i] += __shfl_xor(acc[i], 32);
    const float inv = (l > 0.f) ? __builtin_amdgcn_rcpf(l) : 0.f;

    // each lane finalizes 4 of its 8 channels: lower half i=0..3, upper half i=4..7
    const float a0 = (sel ? acc[4] : acc[0]) * inv;
    const float a1 = (sel ? acc[5] : acc[1]) * inv;
    const float a2 = (sel ? acc[6] : acc[2]) * inv;
    const float a3 = (sel ? acc[7] : acc[3]) * inv;
    const unsigned ib = (unsigned)(sel << 2);  // channel sub-offset 0 or 4

    float4 r;
    if constexpr (std::is_same<RT, float>::value) {
        r = *(const float4*)((const char*)res + ((size_t)n << 10) + (coff << 1) + (ib << 2));
    } else {
        const bf16x4 rb = *(const bf16x4*)((const char*)res + ((size_t)n << 9) + coff + (ib << 1));
        r = make_float4((float)rb[0], (float)rb[1], (float)rb[2], (float)rb[3]);
    }
    const float4 bb = *(const float4*)((const char*)bias + (coff << 1) + (ib << 2));
    float v0 = a0 + r.x + bb.x;
    float v1 = a1 + r.y + bb.y;
    float v2 = a2 + r.z + bb.z;
    float v3 = a3 + r.w + bb.w;
    if (ACT) {
        v0 = fast_mish(v0);
        v1 = fast_mish(v1);
        v2 = fast_mish(v2);
        v3 = fast_mish(v3);
    }
    if constexpr (std::is_same<OT, float>::value) {
        float4 o = {v0, v1, v2, v3};
        *(float4*)((char*)out + ((size_t)n << 10) + (coff << 1) + (ib << 2)) = o;
    } else {
        bf16x4 o;
        o[0] = (bf16)v0; o[1] = (bf16)v1; o[2] = (bf16)v2; o[3] = (bf16)v3;
        *(bf16x4*)((char*)out + ((size_t)n << 9) + coff + (ib << 1)) = o;
    }
}

// ---------------- layer-2 aggregate: wave per node, 4 edge slots x 16 channels ----
// F2f rows are 16 floats (64B, dense; 3.2MB total -> per-XCD-L2 resident).
// F2r holds the residual projection separately. 8 edges/iter for latency hiding.
__global__ void gat_aggregate_small16(const int* __restrict__ row_ptr, const int* __restrict__ csr_src,
                                      const float* __restrict__ el, const float* __restrict__ er,
                                      const unsigned* __restrict__ elmax_u,
                                      const float* __restrict__ F2f, const float* __restrict__ F2r,
                                      const float* __restrict__ bias,
                                      float* __restrict__ out, int N) {
    const int wave = threadIdx.x >> 6;
    const int lane = threadIdx.x & 63;
    int n = blockIdx.x * (blockDim.x >> 6) + wave;
    if (n >= N) return;
    n = __builtin_amdgcn_readfirstlane(n);
    const int slot = lane >> 4;
    const int c = lane & 15;

    const float mx = s2f(elmax_u[8]);
    const float erd = er[n];
    float sh = mx + erd;
    sh = fmaxf(sh, 0.2f * sh);
    constexpr float L2E = 1.4426950408889634f;
    const float C1 = (erd - sh) * L2E;
    const float C2 = fmaf(0.2f, erd, -sh) * L2E;

    const char* csrB = (const char*)csr_src;
    const char* elB = (const char*)el;
    const char* fB = (const char*)F2f;
    const unsigned co = (unsigned)(c << 2);
    const unsigned so = (unsigned)(slot << 2);

    float acc = 0.f, l = 0.f;
    int p = row_ptr[n];
    const int pend = row_ptr[n + 1];
    for (; p + 8 <= pend; p += 8) {
        const int s0 = *(const int*)(csrB + ((unsigned)(p << 2) + so));
        const int s1 = *(const int*)(csrB + ((unsigned)((p + 4) << 2) + so));
        const float e0 = *(const float*)(elB + (unsigned)(s0 << 2));
        const float e1 = *(const float*)(elB + (unsigned)(s1 << 2));
        const float f0 = *(const float*)(fB + ((unsigned)(s0 << 6) + co));
        const float f1 = *(const float*)(fB + ((unsigned)(s1 << 6) + co));
        const float w0 = __builtin_amdgcn_exp2f(
            fmaxf(fmaf(e0, L2E, C1), fmaf(e0, 0.2f * L2E, C2)));
        const float w1 = __builtin_amdgcn_exp2f(
            fmaxf(fmaf(e1, L2E, C1), fmaf(e1, 0.2f * L2E, C2)));
        l += w0 + w1;
        acc = fmaf(w0, f0, fmaf(w1, f1, acc));
    }
    for (; p + 4 <= pend; p += 4) {
        const int s_ = *(const int*)(csrB + ((unsigned)(p << 2) + so));
        const float ev_ = *(const float*)(elB + (unsigned)(s_ << 2));
        const float w_ = __builtin_amdgcn_exp2f(
            fmaxf(fmaf(ev_, L2E, C1), fmaf(ev_, 0.2f * L2E, C2)));
        const float f_ = *(const float*)(fB + ((unsigned)(s_ << 6) + co));
        l += w_;
        acc = fmaf(w_, f_, acc);
    }
    if (p < pend) {  // 1..3 remaining edges, masked by slot
        const int q = p + slot;
        const bool valid = q < pend;
        const int qi = valid ? q : p;
        const int s_ = *(const int*)(csrB + (unsigned)(qi << 2));
        const float ev_ = *(const float*)(elB + (unsigned)(s_ << 2));
        float w_ = __builtin_amdgcn_exp2f(
            fmaxf(fmaf(ev_, L2E, C1), fmaf(ev_, 0.2f * L2E, C2)));
        if (!valid) w_ = 0.f;
        const float f_ = *(const float*)(fB + ((unsigned)(s_ << 6) + co));
        l += w_;
        acc = fmaf(w_, f_, acc);
    }
    l += __shfl_xor(l, 16);
    l += __shfl_xor(l, 32);
    acc += __shfl_xor(acc, 16);
    acc += __shfl_xor(acc, 32);
    const float inv = (l > 0.f) ? __builtin_amdgcn_rcpf(l) : 0.f;
    if (lane < 16) {
        const float rv = F2r[(long)n * 16 + c];
        out[(long)n * 16 + c] = fmaf(acc, inv, rv + bias[c]);
    }
}

// ---------------- host orchestration ----------------

static inline int cdiv(long a, long b) { return (int)((a + b - 1) / b); }

extern "C" void kernel_launch(void* const* d_in, const int* in_sizes, int n_in,
                              void* d_out, int out_size, void* d_ws, size_t ws_size,
                              hipStream_t stream) {
    const float* x   = (const float*)d_in[0];
    const int*   src = (const int*)d_in[1];
    const int*   dst = (const int*)d_in[2];
    const float* W0  = (const float*)d_in[3];
    const float* al0 = (const float*)d_in[4];
    const float* ar0 = (const float*)d_in[5];
    const float* b0  = (const float*)d_in[6];
    const float* W1  = (const float*)d_in[7];
    const float* al1 = (const float*)d_in[8];
    const float* ar1 = (const float*)d_in[9];
    const float* b1  = (const float*)d_in[10];
    const float* W2  = (const float*)d_in[11];
    const float* al2 = (const float*)d_in[12];
    const float* ar2 = (const float*)d_in[13];
    const float* b2  = (const float*)d_in[14];
    const float* rW2 = (const float*)d_in[15];
    float* out = (float*)d_out;

    const int N = in_sizes[0] / 256;   // 50000
    const int E = in_sizes[1];         // 800000

    // workspace layout
    bf16* Wt0    = (bf16*)d_ws;               // 256*256 bf16
    bf16* Wt1    = Wt0 + 65536;               // 256*256 bf16
    bf16* Bct    = Wt1 + 65536;               // 32*256 bf16
    bf16* Fb     = Bct + 8192;                // N*256 bf16 feat
    bf16* Hb     = Fb + (long)N * 256;        // N*256 bf16 hidden
    float* F2f   = (float*)(Hb + (long)N * 256);  // N*16 (layer2 feat, dense)
    float* F2r   = F2f + (long)N * 16;        // N*16 (layer2 residual)
    float* el    = F2r + (long)N * 16;        // N*4
    float* er    = el + (long)N * 4;          // N*4
    unsigned* elmax_u = (unsigned*)(er + (long)N * 4); // 12
    int* deg     = (int*)(elmax_u + 12);      // N
    int* scanned = deg + N;                   // N
    int* bsums   = scanned + N;               // 64
    int* row_ptr = bsums + 64;                // N+1
    int* pos     = row_ptr + N + 1;           // E
    int* csr_src = pos + E;                   // E
    float* bmax  = (float*)(csr_src + E);     // 4 * gridX floats (scratch)

    const int THREADS = 256;
    const int NB = cdiv(N, 1024);
    const int NBY = cdiv(N, 128);             // 391

    // ---------- prep (+deg zero) + CSR build (reused by all layers) ----------
    prep_weights_kernel<<<cdiv(65536, THREADS), THREADS, 0, stream>>>(W0, W1, W2, rW2, Wt0, Wt1, Bct, deg, N);
    count_deg_kernel<<<cdiv(E, THREADS), THREADS, 0, stream>>>(dst, deg, pos, E);
    scan_block_kernel<<<NB, 256, 0, stream>>>(deg, scanned, bsums, N);
    scan_sums_kernel<<<1, 64, 0, stream>>>(bsums, elmax_u, NB);
    apply_offsets_kernel<<<cdiv(N, THREADS), THREADS, 0, stream>>>(scanned, bsums, row_ptr, N, E);
    scatter_kernel<<<cdiv(E, THREADS), THREADS, 0, stream>>>(src, dst, row_ptr, pos, csr_src, E);

    // ================= Layer 0 (H=4, D=64), input x (fp32), out Hb (bf16) =========
    gemm_mfma_bf16<float><<<NBY, 512, 0, stream>>>(x, Wt0, Fb, al0, ar0, el, er, bmax, N);
    reduce_blockmax_kernel<<<1, 256, 0, stream>>>(bmax, NBY, 4, elmax_u);
    gat_aggregate_wave<4, 64, true, float, bf16><<<cdiv(N, 4), 256, 0, stream>>>(
        row_ptr, csr_src, el, er, elmax_u, Fb, x, b0, Hb, N);

    // ================= Layer 1 (H=4, D=64), input Hb (bf16), in-place =============
    gemm_mfma_bf16<bf16><<<NBY, 512, 0, stream>>>(Hb, Wt1, Fb, al1, ar1, el, er, bmax, N);
    reduce_blockmax_kernel<<<1, 256, 0, stream>>>(bmax, NBY, 4, elmax_u + 4);
    gat_aggregate_wave<4, 64, true, bf16, bf16><<<cdiv(N, 4), 256, 0, stream>>>(
        row_ptr, csr_src, el, er, elmax_u + 4, Fb, Hb, b1, Hb, N);

    // ================= Layer 2 (H=1, D=16): F2f|F2r = Hb @ [W2|rW2] ================
    gemm_mfma_n32<<<cdiv(N, 128), 256, 0, stream>>>(Hb, Bct, F2f, F2r, al2, ar2, el, er, bmax, N);
    reduce_blockmax_kernel<<<1, 64, 0, stream>>>(bmax, NBY, 1, elmax_u + 8);
    gat_aggregate_small16<<<cdiv(N, 4), 256, 0, stream>>>(row_ptr, csr_src, el, er, elmax_u,
                                                          F2f, F2r, b2, out, N);
}